// Round 12
// baseline (88.699 us; speedup 1.0000x reference)
//
#include <hip/hip_runtime.h>
#include <hip/hip_bf16.h>
#include <math.h>

typedef __attribute__((ext_vector_type(8))) short short8;
typedef __attribute__((ext_vector_type(4))) float floatx4;

#define MAGIC 0x5EEDBEEFu
// ws layout (single shared copy):
//   flags : 192 u32 at offset 0
//   wredT : 8192 f32 at 64 KB   ([sel][K][h])
//   wmaT  : 64*2048 bf16 at 1 MB (MFMA-B-fragment layout)
#define WS_FLAGS 0u
#define WS_WREDT (64u << 10)
#define WS_WMAT  (1u << 20)

__device__ __forceinline__ float eluf(float v) {
  return v > 0.f ? v : __expf(v) - 1.f;
}

__device__ __forceinline__ unsigned short f2bf(float f) {
  __hip_bfloat16 h = __float2bfloat16(f);
  return *reinterpret_cast<unsigned short*>(&h);
}

// ============ mono kernel: grid 512 x 1024 ============
// blocks 0..191 additionally produce one weight-unit each (parallel, ~1.5us):
//   unit 0..127  : wredT[sel][K][h] for (sel=unit>>6, h=unit&63)
//   unit 128..191: wmaT B-fragment antisym fold for head (unit-128)
// All blocks: x load -> [unit] -> pooled -> rcp rectangle -> poll flags ->
//             MFMA einsum + DI/DD + MLP tail (R7-identical fused path).
__global__ __launch_bounds__(1024, 8) void mono_kernel(
    const float* __restrict__ x,
    const float* __restrict__ wm_di,
    const float* __restrict__ wm_ndi,
    const float* __restrict__ wm_dd,
    const float* __restrict__ b_di, const float* __restrict__ b_ndi,
    const float* __restrict__ b_dd,
    const float* __restrict__ fcw_di, const float* __restrict__ fcb_di,
    const float* __restrict__ fcw_ndi, const float* __restrict__ fcb_ndi,
    const float* __restrict__ fcw_dd, const float* __restrict__ fcb_dd,
    const float* __restrict__ fc1_w, const float* __restrict__ fc1_b,
    const float* __restrict__ fc2_w, const float* __restrict__ fc2_b,
    char* __restrict__ ws,
    float* __restrict__ out) {
  __shared__ float xs[2][256];
  __shared__ __align__(16) union {
    unsigned short ldsA[2][2][2048];  // [plane hi/lo][row][k] bf16 (16 KB)
    float sm[64 * 65];                // producer transpose buffer (16.6 KB)
  } sh;
  __shared__ float pxs[2][64], pds[2][64];
  __shared__ float hp[16][4][2][16];  // [kh][n][row][col] einsum partials
  __shared__ float hh[3][2][64];
  __shared__ float emb_s[2][144];
  __shared__ float f1v_s[2][48];

  const int t = threadIdx.x;
  const int bid = blockIdx.x;
  const int b0 = bid * 2;

  unsigned* __restrict__ flags = (unsigned*)(ws + WS_FLAGS);
  float* __restrict__ wredT = (float*)(ws + WS_WREDT);
  __hip_bfloat16* __restrict__ wmaT_g = (__hip_bfloat16*)(ws + WS_WMAT);

  // ---- x load: 2 rows ----
  if (t < 512) xs[t >> 8][t & 255] = x[(b0 + (t >> 8)) * 256 + (t & 255)];
  __syncthreads();

  // ---- producer: one weight-unit per block (blocks 0..191) ----
  if (bid < 192) {
    const float* __restrict__ w = (bid < 64)  ? wm_di + bid * 4096
                                : (bid < 128) ? wm_dd + (bid - 64) * 4096
                                              : wm_ndi + (bid - 128) * 4096;
#pragma unroll
    for (int i = 0; i < 4; ++i) {
      const int e = i * 1024 + t;
      sh.sm[(e >> 6) * 65 + (e & 63)] = w[e];
    }
    __syncthreads();
    if (bid < 128) {
      // wredT[sel][K][h] = sum_I (w[I][K] - w[K][I]); 16 threads per K
      const int sel = bid >> 6, h = bid & 63;
      const int K = t >> 4, part = t & 15;
      float a = 0.f;
#pragma unroll
      for (int ii = 0; ii < 4; ++ii) {
        const int I = part * 4 + ii;
        a += sh.sm[I * 65 + K] - sh.sm[K * 65 + I];
      }
      a += __shfl_xor(a, 1, 64);
      a += __shfl_xor(a, 2, 64);
      a += __shfl_xor(a, 4, 64);
      a += __shfl_xor(a, 8, 64);
      if (part == 0) wredT[sel * 4096 + K * 64 + h] = a;
    } else {
      // wmaT fold: element ((n*64+kstep)*64+lane)*8+j, h=n*16+(lane&15),
      // k=kstep*32+(lane>>4)*8+j, I=k>>5, J=(I+1+(k&31))&63, dup cols zeroed
      const int h = bid - 128;
      if (t < 256) {
        const int kstep = t >> 2, kc = t & 3;
        const int lane2 = kc * 16 + (h & 15);
        const int n = h >> 4;
        short8 sv;
#pragma unroll
        for (int j = 0; j < 8; ++j) {
          const int k = kstep * 32 + kc * 8 + j;
          const int I = k >> 5, tt2 = k & 31;
          const int J = (I + 1 + tt2) & 63;
          float v = 0.f;
          if (!(tt2 == 31 && I >= 32))
            v = 0.0625f * (sh.sm[I * 65 + J] - sh.sm[J * 65 + I]);
          sv[j] = (short)f2bf(v);
        }
        *(short8*)(wmaT_g + (((n * 64 + kstep) * 64 + lane2) << 3)) = sv;
      }
    }
    __syncthreads();   // all stores issued + sm reads done (rcp reuses union)
    __threadfence();   // device-scope release of produced data
    if (t == 0)
      __hip_atomic_store(&flags[bid], MAGIC, __ATOMIC_RELEASE,
                         __HIP_MEMORY_SCOPE_AGENT);
  }

  // ---- pooled x + telescoped pooled diff (2 waves) ----
  if (t < 128) {
    const int r = t >> 6, m = t & 63;
    const float* __restrict__ xr = xs[r];
    const int b4 = 4 * m;
    pxs[r][m] = 0.25f * (xr[b4] + xr[b4 + 1] + xr[b4 + 2] + xr[b4 + 3]);
    const int i3 = min(b4 + 4, 255), i4 = min(b4 + 5, 255);
    const float smv = 0.2f * (xr[b4 + 1] + xr[b4 + 2] + xr[b4 + 3] + xr[i3] + xr[i4]);
    float prev = __shfl_up(smv, 1, 64);
    if (m == 0) prev = xr[0];
    pds[r][m] = 0.25f * (smv - prev);
  }

  // ---- antisym rcp rectangle -> LDS bf16 hi/lo: 4096 entries, 4/thread ----
  // paired fractions (exact algebra): 8 rcp per entry.
#pragma unroll 1
  for (int i = 0; i < 4; ++i) {
    const int cc = t + i * 1024;
    const int r = cc >> 11, e = cc & 2047;
    const int I = e >> 5;
    const int J = (I + 1 + (e & 31)) & 63;
    const float4 xiv = *(const float4*)&xs[r][I << 2];
    const float4 xjv = *(const float4*)&xs[r][J << 2];
    const float P01 = 2.f * xjv.x * xjv.y + (xjv.x + xjv.y) * 1e-5f;
    const float P23 = 2.f * xjv.z * xjv.w + (xjv.z + xjv.w) * 1e-5f;
    const float ya[4] = {xiv.x, xiv.y, xiv.z, xiv.w};
    float s = 0.f;
#pragma unroll
    for (int a = 0; a < 4; ++a) {
      const float y = ya[a];
      const float u2 = y + 1e-5f;
      const float G = 2.f * y * u2;
      const float D0 = (xjv.x + u2) * (xjv.y + u2);
      const float D1 = (xjv.z + u2) * (xjv.w + u2);
      s += (P01 - G) * __builtin_amdgcn_rcpf(D0);
      s += (P23 - G) * __builtin_amdgcn_rcpf(D1);
    }
    const unsigned short hi = f2bf(s);
    union { unsigned int ub; float f; } hv; hv.ub = ((unsigned int)hi) << 16;
    sh.ldsA[0][r][e] = hi;
    sh.ldsA[1][r][e] = f2bf(s - hv.f);
  }

  // ---- poll all 192 unit flags: one wave, 3 flags/lane, s_sleep backoff ----
  if (t < 64) {
    int it = 0;
    bool ok;
    do {
      const unsigned f0 = __hip_atomic_load(&flags[t], __ATOMIC_ACQUIRE,
                                            __HIP_MEMORY_SCOPE_AGENT);
      const unsigned f1 = __hip_atomic_load(&flags[64 + t], __ATOMIC_ACQUIRE,
                                            __HIP_MEMORY_SCOPE_AGENT);
      const unsigned f2 = __hip_atomic_load(&flags[128 + t], __ATOMIC_ACQUIRE,
                                            __HIP_MEMORY_SCOPE_AGENT);
      ok = __all(f0 == MAGIC && f1 == MAGIC && f2 == MAGIC);
      if (!ok) __builtin_amdgcn_s_sleep(8);
    } while (!ok && ++it < (1 << 20));
  }
  __syncthreads();  // rcp LDS ready + flags observed -> einsum may read ws

  // ---- MFMA einsum: wave kh owns K-slice of 128; n-outer to keep regs low ----
  {
    const int kh = t >> 6, lane = t & 63;
    const int arow = lane & 1;
    const int kofs = kh * 128 + ((lane >> 4) << 3);
    const short* __restrict__ wmaT = (const short*)wmaT_g;
#pragma unroll
    for (int n = 0; n < 4; ++n) {
      floatx4 acc = {0.f, 0.f, 0.f, 0.f};
#pragma unroll
      for (int s = 0; s < 4; ++s) {
        const int kk = kofs + s * 32;
        const short8 ah = *(const short8*)&sh.ldsA[0][arow][kk];
        const short8 al = *(const short8*)&sh.ldsA[1][arow][kk];
        const int kstep = kh * 4 + s;
        const short8 bv = *(const short8*)(wmaT + (((n * 64 + kstep) * 64 + lane) << 3));
        acc = __builtin_amdgcn_mfma_f32_16x16x32_bf16(ah, bv, acc, 0, 0, 0);
        acc = __builtin_amdgcn_mfma_f32_16x16x32_bf16(al, bv, acc, 0, 0, 0);
      }
      // C/D layout (m89): col=lane&15, row=(lane>>4)*4+reg -> rows 0,1 in lanes 0..15
      if (lane < 16) {
        hp[kh][n][0][lane] = acc[0];
        hp[kh][n][1][lane] = acc[1];
      }
    }
  }

  // ---- DI/DD separable projections (same barrier interval) ----
  if (t < 128) {
    const int r = t >> 6, h = t & 63;
    float adi = b_di[h], add_ = b_dd[h];
#pragma unroll 8
    for (int K = 0; K < 64; ++K) {
      adi += pxs[r][K] * wredT[K * 64 + h];
      add_ += pds[r][K] * wredT[4096 + K * 64 + h];
    }
    hh[0][r][h] = eluf(adi);
    hh[2][r][h] = eluf(add_);
  }
  __syncthreads();

  // ---- combine K-slice partials -> NDI heads ----
  if (t < 128) {
    const int row = t >> 6, h = t & 63;
    const int n = h >> 4, c = h & 15;
    float v = b_ndi[h];
#pragma unroll
    for (int kh = 0; kh < 16; ++kh) v += hp[kh][n][row][c];
    hh[1][row][h] = eluf(v);
  }
  __syncthreads();

  // ---- per-picker fc: HEAD(64) -> EMB(48) ----
  if (t < 2 * 144) {
    const int r = t / 144;
    const int k = t - r * 144;
    const int pick = k / 48;
    const int e = k - pick * 48;
    const float* __restrict__ fw = (pick == 0) ? fcw_di : (pick == 1) ? fcw_ndi : fcw_dd;
    const float* __restrict__ fb = (pick == 0) ? fcb_di : (pick == 1) ? fcb_ndi : fcb_dd;
    float a = fb[e];
#pragma unroll 8
    for (int hq = 0; hq < 64; ++hq) a += hh[pick][r][hq] * fw[e * 64 + hq];
    emb_s[r][k] = eluf(a);
  }
  __syncthreads();

  // ---- fc1: 144 -> 48, elu ----
  if (t < 2 * 48) {
    const int r = t / 48, o = t - (t / 48) * 48;
    float a = fc1_b[o];
#pragma unroll 8
    for (int k = 0; k < 144; ++k) a += emb_s[r][k] * fc1_w[o * 144 + k];
    f1v_s[r][o] = eluf(a);
  }
  __syncthreads();

  // ---- fc2: 48 -> 20 ----
  if (t < 2 * 20) {
    const int r = t / 20, o = t - (t / 20) * 20;
    float a = fc2_b[o];
#pragma unroll
    for (int j = 0; j < 48; ++j) a += f1v_s[r][j] * fc2_w[o * 48 + j];
    out[(b0 + r) * 20 + o] = a;
  }
}

extern "C" void kernel_launch(void* const* d_in, const int* in_sizes, int n_in,
                              void* d_out, int out_size, void* d_ws, size_t ws_size,
                              hipStream_t stream) {
  const float* x       = (const float*)d_in[0];
  const float* wm_di   = (const float*)d_in[1];
  const float* b_di    = (const float*)d_in[2];
  const float* fcw_di  = (const float*)d_in[3];
  const float* fcb_di  = (const float*)d_in[4];
  const float* wm_ndi  = (const float*)d_in[5];
  const float* b_ndi   = (const float*)d_in[6];
  const float* fcw_ndi = (const float*)d_in[7];
  const float* fcb_ndi = (const float*)d_in[8];
  const float* wm_dd   = (const float*)d_in[9];
  const float* b_dd    = (const float*)d_in[10];
  const float* fcw_dd  = (const float*)d_in[11];
  const float* fcb_dd  = (const float*)d_in[12];
  const float* fc1_w   = (const float*)d_in[13];
  const float* fc1_b   = (const float*)d_in[14];
  const float* fc2_w   = (const float*)d_in[15];
  const float* fc2_b   = (const float*)d_in[16];
  float* out = (float*)d_out;
  char* ws = (char*)d_ws;

  mono_kernel<<<512, 1024, 0, stream>>>(
      x, wm_di, wm_ndi, wm_dd, b_di, b_ndi, b_dd,
      fcw_di, fcb_di, fcw_ndi, fcb_ndi, fcw_dd, fcb_dd,
      fc1_w, fc1_b, fc2_w, fc2_b, ws, out);
}

// Round 13
// 27.968 us; speedup vs baseline: 3.1714x; 3.1714x over previous
//
#include <hip/hip_runtime.h>
#include <hip/hip_bf16.h>
#include <math.h>

typedef __attribute__((ext_vector_type(8))) short short8;
typedef __attribute__((ext_vector_type(4))) float floatx4;

// ---- workspace layout ----
#define WS_WREDT 0u          // 8192 f32 (32 KB), [sel][K][h]
#define WS_WMAT  (1u << 20)  // 4*64*64*8 bf16 = 256 KB, B-fragment-swizzled

__device__ __forceinline__ float eluf(float v) {
  return v > 0.f ? v : __expf(v) - 1.f;
}

__device__ __forceinline__ unsigned short f2bf(float f) {
  __hip_bfloat16 h = __float2bfloat16(f);
  return *reinterpret_cast<unsigned short*>(&h);
}

// ============ prep ============
// blocks 0..127: wredT[sel][K][h] = colsum-rowsum of wm_di/wm_dd head h (LDS transpose)
// blocks 128..191: per-head wmaT fold into MFMA-B-fragment layout:
//   element ((n*64+kstep)*64+lane)*8+j = bf16(0.0625*(w[h,I,J]-w[h,J,I])),
//   h=n*16+(lane&15), k=kstep*32+(lane>>4)*8+j, I=k>>5, J=(I+1+(k&31))&63,
//   duplicate d=32 columns (k&31==31 && I>=32) zeroed.
__global__ __launch_bounds__(256) void prep_kernel(
    const float* __restrict__ wm_di,
    const float* __restrict__ wm_ndi,
    const float* __restrict__ wm_dd,
    char* __restrict__ ws) {
  __shared__ float sm[64 * 65];
  const int t = threadIdx.x;
  if (blockIdx.x < 128) {
    const int sel = blockIdx.x >> 6, h = blockIdx.x & 63;
    const float* w = (sel ? wm_dd : wm_di) + h * 4096;
#pragma unroll 4
    for (int i = 0; i < 16; ++i) {
      const int e = i * 256 + t;
      sm[(e >> 6) * 65 + (e & 63)] = w[e];
    }
    __syncthreads();
    if (t < 64) {
      float cs = 0.f, rs = 0.f;
#pragma unroll 8
      for (int I = 0; I < 64; ++I) {
        cs += sm[I * 65 + t];
        rs += sm[t * 65 + I];
      }
      ((float*)(ws + WS_WREDT))[sel * 4096 + t * 64 + h] = cs - rs;
    }
  } else {
    const int h = blockIdx.x - 128;  // 0..63
    const float* w = wm_ndi + h * 4096;
#pragma unroll 4
    for (int i = 0; i < 16; ++i) {
      const int e = i * 256 + t;
      sm[(e >> 6) * 65 + (e & 63)] = w[e];
    }
    __syncthreads();
    const int kstep = t >> 2, kc = t & 3;
    const int lane = kc * 16 + (h & 15);
    const int n = h >> 4;
    short8 sv;
#pragma unroll
    for (int j = 0; j < 8; ++j) {
      const int k = kstep * 32 + kc * 8 + j;
      const int I = k >> 5, tt = k & 31;
      const int J = (I + 1 + tt) & 63;
      float v = 0.f;
      if (!(tt == 31 && I >= 32))
        v = 0.0625f * (sm[I * 65 + J] - sm[J * 65 + I]);
      sv[j] = (short)f2bf(v);
    }
    *(short8*)((__hip_bfloat16*)(ws + WS_WMAT) + (((n * 64 + kstep) * 64 + lane) << 3)) = sv;
  }
}

// ============ fused: paired-rcp rectangle -> in-LDS MFMA einsum -> MLP tail ============
// grid 512, 1024 threads (16 waves), 2 batch rows per block
__global__ __launch_bounds__(1024, 8) void fused_kernel(
    const float* __restrict__ x,
    const float* __restrict__ b_di, const float* __restrict__ b_ndi,
    const float* __restrict__ b_dd,
    const float* __restrict__ fcw_di, const float* __restrict__ fcb_di,
    const float* __restrict__ fcw_ndi, const float* __restrict__ fcb_ndi,
    const float* __restrict__ fcw_dd, const float* __restrict__ fcb_dd,
    const float* __restrict__ fc1_w, const float* __restrict__ fc1_b,
    const float* __restrict__ fc2_w, const float* __restrict__ fc2_b,
    const char* __restrict__ ws,
    float* __restrict__ out) {
  __shared__ float xs[2][256];
  __shared__ __align__(16) unsigned short ldsA[2][2][2048];  // [plane hi/lo][row][k] bf16
  __shared__ float pxs[2][64], pds[2][64];
  __shared__ float hp[16][4][2][16];  // [kh][n][row][col] einsum partials
  __shared__ float hh[3][2][64];
  __shared__ float emb_s[2][144];
  __shared__ float f1v_s[2][48];

  const int t = threadIdx.x;
  const int b0 = blockIdx.x * 2;
  const float* __restrict__ wredT = (const float*)(ws + WS_WREDT);  // [sel][K][h]
  const short* __restrict__ wmaT = (const short*)(ws + WS_WMAT);

  if (t < 512) xs[t >> 8][t & 255] = x[(b0 + (t >> 8)) * 256 + (t & 255)];
  __syncthreads();

  // ---- pooled x + telescoped pooled diff (2 waves) ----
  if (t < 128) {
    const int r = t >> 6, m = t & 63;
    const float* __restrict__ xr = xs[r];
    const int b4 = 4 * m;
    pxs[r][m] = 0.25f * (xr[b4] + xr[b4 + 1] + xr[b4 + 2] + xr[b4 + 3]);
    const int i3 = min(b4 + 4, 255), i4 = min(b4 + 5, 255);
    const float smv = 0.2f * (xr[b4 + 1] + xr[b4 + 2] + xr[b4 + 3] + xr[i3] + xr[i4]);
    float prev = __shfl_up(smv, 1, 64);
    if (m == 0) prev = xr[0];
    pds[r][m] = 0.25f * (smv - prev);
  }

  // ---- antisym rcp rectangle -> LDS bf16 hi/lo ----
  // Thread t owns row r = t>>9 and 4 consecutive entries e0..e0+3 (same
  // I-group -> xiv loaded ONCE). Paired fractions: 8 rcp per entry.
  {
    const int r = t >> 9;
    const int e0 = (t & 511) * 4;
    const int I = e0 >> 5;
    const float4 xiv = *(const float4*)&xs[r][I << 2];
    float ua[4], Ga[4];
    {
      const float ya[4] = {xiv.x, xiv.y, xiv.z, xiv.w};
#pragma unroll
      for (int a = 0; a < 4; ++a) {
        ua[a] = ya[a] + 1e-5f;
        Ga[a] = 2.f * ya[a] * ua[a];
      }
    }
#pragma unroll
    for (int i = 0; i < 4; ++i) {
      const int e = e0 + i;
      const int J = (I + 1 + (e & 31)) & 63;
      const float4 xjv = *(const float4*)&xs[r][J << 2];
      const float P01 = 2.f * xjv.x * xjv.y + (xjv.x + xjv.y) * 1e-5f;
      const float P23 = 2.f * xjv.z * xjv.w + (xjv.z + xjv.w) * 1e-5f;
      float s = 0.f;
#pragma unroll
      for (int a = 0; a < 4; ++a) {
        const float D0 = (xjv.x + ua[a]) * (xjv.y + ua[a]);
        const float D1 = (xjv.z + ua[a]) * (xjv.w + ua[a]);
        s += (P01 - Ga[a]) * __builtin_amdgcn_rcpf(D0);
        s += (P23 - Ga[a]) * __builtin_amdgcn_rcpf(D1);
      }
      const unsigned short hi = f2bf(s);
      union { unsigned int uu; float f; } hv; hv.uu = ((unsigned int)hi) << 16;
      ldsA[0][r][e] = hi;
      ldsA[1][r][e] = f2bf(s - hv.f);
    }
  }
  __syncthreads();

  // ---- MFMA einsum: wave kh owns K-slice of 128; s-OUTER so A-fragments are
  //      loaded once per s (8 ds_read_b128/wave instead of 32) ----
  {
    const int kh = t >> 6, lane = t & 63;
    const int arow = lane & 1;
    const int kofs = kh * 128 + ((lane >> 4) << 3);
    floatx4 acc0 = {0.f, 0.f, 0.f, 0.f}, acc1 = {0.f, 0.f, 0.f, 0.f};
    floatx4 acc2 = {0.f, 0.f, 0.f, 0.f}, acc3 = {0.f, 0.f, 0.f, 0.f};
#pragma unroll
    for (int s = 0; s < 4; ++s) {
      const int kk = kofs + s * 32;
      const short8 ah = *(const short8*)&ldsA[0][arow][kk];
      const short8 al = *(const short8*)&ldsA[1][arow][kk];
      const int base = ((kh * 4 + s) * 64 + lane) << 3;  // n stride = 32768
      const short8 bv0 = *(const short8*)(wmaT + base);
      const short8 bv1 = *(const short8*)(wmaT + base + 32768);
      const short8 bv2 = *(const short8*)(wmaT + base + 65536);
      const short8 bv3 = *(const short8*)(wmaT + base + 98304);
      acc0 = __builtin_amdgcn_mfma_f32_16x16x32_bf16(ah, bv0, acc0, 0, 0, 0);
      acc0 = __builtin_amdgcn_mfma_f32_16x16x32_bf16(al, bv0, acc0, 0, 0, 0);
      acc1 = __builtin_amdgcn_mfma_f32_16x16x32_bf16(ah, bv1, acc1, 0, 0, 0);
      acc1 = __builtin_amdgcn_mfma_f32_16x16x32_bf16(al, bv1, acc1, 0, 0, 0);
      acc2 = __builtin_amdgcn_mfma_f32_16x16x32_bf16(ah, bv2, acc2, 0, 0, 0);
      acc2 = __builtin_amdgcn_mfma_f32_16x16x32_bf16(al, bv2, acc2, 0, 0, 0);
      acc3 = __builtin_amdgcn_mfma_f32_16x16x32_bf16(ah, bv3, acc3, 0, 0, 0);
      acc3 = __builtin_amdgcn_mfma_f32_16x16x32_bf16(al, bv3, acc3, 0, 0, 0);
    }
    // C/D layout (m89): col=lane&15, row=(lane>>4)*4+reg -> rows 0,1 in lanes 0..15
    if (lane < 16) {
      hp[kh][0][0][lane] = acc0[0]; hp[kh][0][1][lane] = acc0[1];
      hp[kh][1][0][lane] = acc1[0]; hp[kh][1][1][lane] = acc1[1];
      hp[kh][2][0][lane] = acc2[0]; hp[kh][2][1][lane] = acc2[1];
      hp[kh][3][0][lane] = acc3[0]; hp[kh][3][1][lane] = acc3[1];
    }
  }

  // ---- DI/DD separable projections (same barrier interval) ----
  if (t < 128) {
    const int r = t >> 6, h = t & 63;
    float adi = b_di[h], add_ = b_dd[h];
#pragma unroll 8
    for (int K = 0; K < 64; ++K) {
      adi += pxs[r][K] * wredT[K * 64 + h];
      add_ += pds[r][K] * wredT[4096 + K * 64 + h];
    }
    hh[0][r][h] = eluf(adi);
    hh[2][r][h] = eluf(add_);
  }
  __syncthreads();

  // ---- combine K-slice partials -> NDI heads ----
  if (t < 128) {
    const int row = t >> 6, h = t & 63;
    const int n = h >> 4, c = h & 15;
    float v = b_ndi[h];
#pragma unroll
    for (int kh = 0; kh < 16; ++kh) v += hp[kh][n][row][c];
    hh[1][row][h] = eluf(v);
  }
  __syncthreads();

  // ---- per-picker fc: HEAD(64) -> EMB(48) ----
  if (t < 2 * 144) {
    const int r = t / 144;
    const int k = t - r * 144;
    const int pick = k / 48;
    const int e = k - pick * 48;
    const float* __restrict__ fw = (pick == 0) ? fcw_di : (pick == 1) ? fcw_ndi : fcw_dd;
    const float* __restrict__ fb = (pick == 0) ? fcb_di : (pick == 1) ? fcb_ndi : fcb_dd;
    float a = fb[e];
#pragma unroll 8
    for (int hq = 0; hq < 64; ++hq) a += hh[pick][r][hq] * fw[e * 64 + hq];
    emb_s[r][k] = eluf(a);
  }
  __syncthreads();

  // ---- fc1: 144 -> 48, elu ----
  if (t < 2 * 48) {
    const int r = t / 48, o = t - (t / 48) * 48;
    float a = fc1_b[o];
#pragma unroll 8
    for (int k = 0; k < 144; ++k) a += emb_s[r][k] * fc1_w[o * 144 + k];
    f1v_s[r][o] = eluf(a);
  }
  __syncthreads();

  // ---- fc2: 48 -> 20 ----
  if (t < 2 * 20) {
    const int r = t / 20, o = t - (t / 20) * 20;
    float a = fc2_b[o];
#pragma unroll
    for (int j = 0; j < 48; ++j) a += f1v_s[r][j] * fc2_w[o * 48 + j];
    out[(b0 + r) * 20 + o] = a;
  }
}

extern "C" void kernel_launch(void* const* d_in, const int* in_sizes, int n_in,
                              void* d_out, int out_size, void* d_ws, size_t ws_size,
                              hipStream_t stream) {
  const float* x       = (const float*)d_in[0];
  const float* wm_di   = (const float*)d_in[1];
  const float* b_di    = (const float*)d_in[2];
  const float* fcw_di  = (const float*)d_in[3];
  const float* fcb_di  = (const float*)d_in[4];
  const float* wm_ndi  = (const float*)d_in[5];
  const float* b_ndi   = (const float*)d_in[6];
  const float* fcw_ndi = (const float*)d_in[7];
  const float* fcb_ndi = (const float*)d_in[8];
  const float* wm_dd   = (const float*)d_in[9];
  const float* b_dd    = (const float*)d_in[10];
  const float* fcw_dd  = (const float*)d_in[11];
  const float* fcb_dd  = (const float*)d_in[12];
  const float* fc1_w   = (const float*)d_in[13];
  const float* fc1_b   = (const float*)d_in[14];
  const float* fc2_w   = (const float*)d_in[15];
  const float* fc2_b   = (const float*)d_in[16];
  float* out = (float*)d_out;
  char* ws = (char*)d_ws;

  prep_kernel<<<192, 256, 0, stream>>>(wm_di, wm_ndi, wm_dd, ws);
  fused_kernel<<<512, 1024, 0, stream>>>(
      x, b_di, b_ndi, b_dd,
      fcw_di, fcb_di, fcw_ndi, fcb_ndi, fcw_dd, fcb_dd,
      fc1_w, fc1_b, fc2_w, fc2_b, ws, out);
}

// Round 14
// 26.225 us; speedup vs baseline: 3.3822x; 1.0665x over previous
//
#include <hip/hip_runtime.h>
#include <hip/hip_bf16.h>
#include <math.h>

typedef __attribute__((ext_vector_type(8))) short short8;
typedef __attribute__((ext_vector_type(4))) float floatx4;

// ---- workspace layout ----
// f32 index space at ws base (the "tailpack", copied to LDS by fused):
//   [0)      wredT   [2][64][64]   ([sel][K][h])
//   [8192)   fcwT_di [64][48]      (transposed: [hq][e])
//   [11264)  fcwT_ndi[64][48]
//   [14336)  fcwT_dd [64][48]
//   [17408)  fc1T    [144][48]     (transposed: [k][o])
//   [24320)  b_di(64) b_ndi(64) b_dd(64) fcb_di(48) fcb_ndi(48) fcb_dd(48) fc1_b(48)
//   total 24704 f32 = 96.5 KB
#define TP_FCW   8192
#define TP_FC1   17408
#define TP_BIAS  24320
#define TP_N     24704
#define WS_WMAT  (1u << 20)  // 64*2048 bf16, MFMA-B-fragment layout

__device__ __forceinline__ float eluf(float v) {
  return v > 0.f ? v : __expf(v) - 1.f;
}

__device__ __forceinline__ unsigned short f2bf(float f) {
  __hip_bfloat16 h = __float2bfloat16(f);
  return *reinterpret_cast<unsigned short*>(&h);
}

// ============ prep: 197 blocks ============
__global__ __launch_bounds__(256) void prep_kernel(
    const float* __restrict__ wm_di,
    const float* __restrict__ wm_ndi,
    const float* __restrict__ wm_dd,
    const float* __restrict__ b_di, const float* __restrict__ b_ndi,
    const float* __restrict__ b_dd,
    const float* __restrict__ fcw_di, const float* __restrict__ fcw_ndi,
    const float* __restrict__ fcw_dd,
    const float* __restrict__ fcb_di, const float* __restrict__ fcb_ndi,
    const float* __restrict__ fcb_dd,
    const float* __restrict__ fc1_w, const float* __restrict__ fc1_b,
    char* __restrict__ ws) {
  __shared__ float sm[64 * 65];
  const int t = threadIdx.x;
  float* wsf = (float*)ws;
  const int b = blockIdx.x;
  if (b < 128) {
    const int sel = b >> 6, h = b & 63;
    const float* w = (sel ? wm_dd : wm_di) + h * 4096;
#pragma unroll 4
    for (int i = 0; i < 16; ++i) {
      const int e = i * 256 + t;
      sm[(e >> 6) * 65 + (e & 63)] = w[e];
    }
    __syncthreads();
    if (t < 64) {
      float cs = 0.f, rs = 0.f;
#pragma unroll 8
      for (int I = 0; I < 64; ++I) {
        cs += sm[I * 65 + t];
        rs += sm[t * 65 + I];
      }
      wsf[sel * 4096 + t * 64 + h] = cs - rs;
    }
  } else if (b < 192) {
    const int h = b - 128;  // 0..63
    const float* w = wm_ndi + h * 4096;
#pragma unroll 4
    for (int i = 0; i < 16; ++i) {
      const int e = i * 256 + t;
      sm[(e >> 6) * 65 + (e & 63)] = w[e];
    }
    __syncthreads();
    const int kstep = t >> 2, kc = t & 3;
    const int lane = kc * 16 + (h & 15);
    const int n = h >> 4;
    short8 sv;
#pragma unroll
    for (int j = 0; j < 8; ++j) {
      const int k = kstep * 32 + kc * 8 + j;
      const int I = k >> 5, tt = k & 31;
      const int J = (I + 1 + tt) & 63;
      float v = 0.f;
      if (!(tt == 31 && I >= 32))
        v = 0.0625f * (sm[I * 65 + J] - sm[J * 65 + I]);
      sv[j] = (short)f2bf(v);
    }
    *(short8*)((__hip_bfloat16*)(ws + WS_WMAT) + (((n * 64 + kstep) * 64 + lane) << 3)) = sv;
  } else if (b < 195) {
    // fcw transpose: [e][hq] -> tp[TP_FCW + pick*3072 + hq*48 + e]
    const int pick = b - 192;
    const float* src = (pick == 0) ? fcw_di : (pick == 1) ? fcw_ndi : fcw_dd;
    for (int i = t; i < 3072; i += 256) {
      const int e = i >> 6, hq = i & 63;
      wsf[TP_FCW + pick * 3072 + hq * 48 + e] = src[i];
    }
  } else if (b == 195) {
    // fc1 transpose: [o][k] -> tp[TP_FC1 + k*48 + o]
    for (int i = t; i < 6912; i += 256) {
      const int o = i / 144, k = i - o * 144;
      wsf[TP_FC1 + k * 48 + o] = fc1_w[i];
    }
  } else {
    // biases, contiguous at TP_BIAS
    for (int i = t; i < 384; i += 256) {
      float v;
      if (i < 64) v = b_di[i];
      else if (i < 128) v = b_ndi[i - 64];
      else if (i < 192) v = b_dd[i - 128];
      else if (i < 240) v = fcb_di[i - 192];
      else if (i < 288) v = fcb_ndi[i - 240];
      else if (i < 336) v = fcb_dd[i - 288];
      else v = fc1_b[i - 336];
      wsf[TP_BIAS + i] = v;
    }
  }
}

// ============ fused: grid 256, 1024 threads, BB=4 ============
__global__ __launch_bounds__(1024, 4) void fused_kernel(
    const float* __restrict__ x,
    const float* __restrict__ fc2_w, const float* __restrict__ fc2_b,
    const char* __restrict__ ws,
    float* __restrict__ out) {
  __shared__ float xs[4][256];
  __shared__ __align__(16) unsigned short ldsA[2][4][2048];  // [plane][row][k]
  __shared__ float pxs[4][64], pds[4][64];
  __shared__ float hp[16][4][4][16];  // [kh][n][row][col]
  __shared__ float hh[3][4][64];
  __shared__ float emb_s[4][144];
  __shared__ float f1v_s[4][48];
  __shared__ __align__(16) float tp[TP_N];  // 96.5 KB tailpack

  const int t = threadIdx.x;
  const int b0 = blockIdx.x * 4;
  const short* __restrict__ wmaT = (const short*)(ws + WS_WMAT);
  const float4* __restrict__ ws4 = (const float4*)ws;
  float4* __restrict__ tp4 = (float4*)tp;

  xs[t >> 8][t & 255] = x[(b0 + (t >> 8)) * 256 + (t & 255)];
  __syncthreads();

  // ---- tailpack copy: 6176 float4 (loads issue early, overlap follows) ----
#pragma unroll
  for (int j = 0; j < 7; ++j) {
    const int idx = t + j * 1024;
    if (idx < TP_N / 4) tp4[idx] = ws4[idx];
  }

  // ---- pooled x + telescoped pooled diff ----
  if (t < 256) {
    const int r = t >> 6, m = t & 63;
    const float* __restrict__ xr = xs[r];
    const int b4 = 4 * m;
    pxs[r][m] = 0.25f * (xr[b4] + xr[b4 + 1] + xr[b4 + 2] + xr[b4 + 3]);
    const int i3 = min(b4 + 4, 255), i4 = min(b4 + 5, 255);
    const float smv = 0.2f * (xr[b4 + 1] + xr[b4 + 2] + xr[b4 + 3] + xr[i3] + xr[i4]);
    float prev = __shfl_up(smv, 1, 64);
    if (m == 0) prev = xr[0];
    pds[r][m] = 0.25f * (smv - prev);
  }

  // ---- antisym rcp rectangle -> ldsA (hi/lo): 2 I-groups of 4 per thread ----
#pragma unroll
  for (int gi = 0; gi < 2; ++gi) {
    const int g = t + gi * 1024;       // 0..2047
    const int r = g >> 9;
    const int e0 = (g & 511) * 4;
    const int I = e0 >> 5;
    const float4 xiv = *(const float4*)&xs[r][I << 2];
    float ua[4], Ga[4];
    {
      const float ya[4] = {xiv.x, xiv.y, xiv.z, xiv.w};
#pragma unroll
      for (int a = 0; a < 4; ++a) {
        ua[a] = ya[a] + 1e-5f;
        Ga[a] = 2.f * ya[a] * ua[a];
      }
    }
#pragma unroll
    for (int i = 0; i < 4; ++i) {
      const int e = e0 + i;
      const int J = (I + 1 + (e & 31)) & 63;
      const float4 xjv = *(const float4*)&xs[r][J << 2];
      const float P01 = 2.f * xjv.x * xjv.y + (xjv.x + xjv.y) * 1e-5f;
      const float P23 = 2.f * xjv.z * xjv.w + (xjv.z + xjv.w) * 1e-5f;
      float s = 0.f;
#pragma unroll
      for (int a = 0; a < 4; ++a) {
        const float D0 = (xjv.x + ua[a]) * (xjv.y + ua[a]);
        const float D1 = (xjv.z + ua[a]) * (xjv.w + ua[a]);
        s += (P01 - Ga[a]) * __builtin_amdgcn_rcpf(D0);
        s += (P23 - Ga[a]) * __builtin_amdgcn_rcpf(D1);
      }
      const unsigned short hi = f2bf(s);
      union { unsigned int uu; float f; } hv; hv.uu = ((unsigned int)hi) << 16;
      ldsA[0][r][e] = hi;
      ldsA[1][r][e] = f2bf(s - hv.f);
    }
  }
  __syncthreads();

  // ---- MFMA einsum: s-outer, 4 N-accumulators; A rows 0..3 real ----
  {
    const int kh = t >> 6, lane = t & 63;
    const int arow = (lane & 15) & 3;
    const int kofs = kh * 128 + ((lane >> 4) << 3);
    floatx4 acc0 = {0.f, 0.f, 0.f, 0.f}, acc1 = {0.f, 0.f, 0.f, 0.f};
    floatx4 acc2 = {0.f, 0.f, 0.f, 0.f}, acc3 = {0.f, 0.f, 0.f, 0.f};
#pragma unroll
    for (int s = 0; s < 4; ++s) {
      const int kk = kofs + s * 32;
      const short8 ah = *(const short8*)&ldsA[0][arow][kk];
      const short8 al = *(const short8*)&ldsA[1][arow][kk];
      const int base = ((kh * 4 + s) * 64 + lane) << 3;  // n-stride 32768
      const short8 bv0 = *(const short8*)(wmaT + base);
      const short8 bv1 = *(const short8*)(wmaT + base + 32768);
      const short8 bv2 = *(const short8*)(wmaT + base + 65536);
      const short8 bv3 = *(const short8*)(wmaT + base + 98304);
      acc0 = __builtin_amdgcn_mfma_f32_16x16x32_bf16(ah, bv0, acc0, 0, 0, 0);
      acc0 = __builtin_amdgcn_mfma_f32_16x16x32_bf16(al, bv0, acc0, 0, 0, 0);
      acc1 = __builtin_amdgcn_mfma_f32_16x16x32_bf16(ah, bv1, acc1, 0, 0, 0);
      acc1 = __builtin_amdgcn_mfma_f32_16x16x32_bf16(al, bv1, acc1, 0, 0, 0);
      acc2 = __builtin_amdgcn_mfma_f32_16x16x32_bf16(ah, bv2, acc2, 0, 0, 0);
      acc2 = __builtin_amdgcn_mfma_f32_16x16x32_bf16(al, bv2, acc2, 0, 0, 0);
      acc3 = __builtin_amdgcn_mfma_f32_16x16x32_bf16(ah, bv3, acc3, 0, 0, 0);
      acc3 = __builtin_amdgcn_mfma_f32_16x16x32_bf16(al, bv3, acc3, 0, 0, 0);
    }
    // C/D (m89): col=lane&15, row=(lane>>4)*4+reg -> rows 0..3 = lanes<16, regs 0..3
    if (lane < 16) {
#pragma unroll
      for (int r = 0; r < 4; ++r) {
        hp[kh][0][r][lane] = acc0[r];
        hp[kh][1][r][lane] = acc1[r];
        hp[kh][2][r][lane] = acc2[r];
        hp[kh][3][r][lane] = acc3[r];
      }
    }
  }

  // ---- DI/DD projections from LDS tailpack (same barrier interval) ----
  if (t < 256) {
    const int r = t >> 6, h = t & 63;
    float adi = tp[TP_BIAS + h], add_ = tp[TP_BIAS + 128 + h];
#pragma unroll 8
    for (int K = 0; K < 64; ++K) {
      adi += pxs[r][K] * tp[K * 64 + h];
      add_ += pds[r][K] * tp[4096 + K * 64 + h];
    }
    hh[0][r][h] = eluf(adi);
    hh[2][r][h] = eluf(add_);
  }
  __syncthreads();

  // ---- combine K-slice partials -> NDI heads ----
  if (t < 256) {
    const int row = t >> 6, h = t & 63;
    const int n = h >> 4, c = h & 15;
    float v = tp[TP_BIAS + 64 + h];
#pragma unroll
    for (int kh = 0; kh < 16; ++kh) v += hp[kh][n][row][c];
    hh[1][row][h] = eluf(v);
  }
  __syncthreads();

  // ---- per-picker fc from LDS (transposed fcwT: [hq][e]) ----
  if (t < 4 * 144) {
    const int r = t / 144;
    const int k = t - r * 144;
    const int pick = k / 48;
    const int e = k - pick * 48;
    const float* __restrict__ fwt = tp + TP_FCW + pick * 3072;
    float a = tp[TP_BIAS + 192 + pick * 48 + e];
#pragma unroll 8
    for (int hq = 0; hq < 64; ++hq) a += hh[pick][r][hq] * fwt[hq * 48 + e];
    emb_s[r][k] = eluf(a);
  }
  __syncthreads();

  // ---- fc1 from LDS (transposed fc1T: [k][o]) ----
  if (t < 4 * 48) {
    const int r = t / 48, o = t - (t / 48) * 48;
    float a = tp[TP_BIAS + 336 + o];
#pragma unroll 8
    for (int k = 0; k < 144; ++k) a += emb_s[r][k] * tp[TP_FC1 + k * 48 + o];
    f1v_s[r][o] = eluf(a);
  }
  __syncthreads();

  // ---- fc2: 48 -> 20 (global weights; tiny) ----
  if (t < 4 * 20) {
    const int r = t / 20, o = t - (t / 20) * 20;
    float a = fc2_b[o];
#pragma unroll
    for (int j = 0; j < 48; ++j) a += f1v_s[r][j] * fc2_w[o * 48 + j];
    out[(b0 + r) * 20 + o] = a;
  }
}

extern "C" void kernel_launch(void* const* d_in, const int* in_sizes, int n_in,
                              void* d_out, int out_size, void* d_ws, size_t ws_size,
                              hipStream_t stream) {
  const float* x       = (const float*)d_in[0];
  const float* wm_di   = (const float*)d_in[1];
  const float* b_di    = (const float*)d_in[2];
  const float* fcw_di  = (const float*)d_in[3];
  const float* fcb_di  = (const float*)d_in[4];
  const float* wm_ndi  = (const float*)d_in[5];
  const float* b_ndi   = (const float*)d_in[6];
  const float* fcw_ndi = (const float*)d_in[7];
  const float* fcb_ndi = (const float*)d_in[8];
  const float* wm_dd   = (const float*)d_in[9];
  const float* b_dd    = (const float*)d_in[10];
  const float* fcw_dd  = (const float*)d_in[11];
  const float* fcb_dd  = (const float*)d_in[12];
  const float* fc1_w   = (const float*)d_in[13];
  const float* fc1_b   = (const float*)d_in[14];
  const float* fc2_w   = (const float*)d_in[15];
  const float* fc2_b   = (const float*)d_in[16];
  float* out = (float*)d_out;
  char* ws = (char*)d_ws;

  prep_kernel<<<197, 256, 0, stream>>>(
      wm_di, wm_ndi, wm_dd, b_di, b_ndi, b_dd,
      fcw_di, fcw_ndi, fcw_dd, fcb_di, fcb_ndi, fcb_dd,
      fc1_w, fc1_b, ws);
  fused_kernel<<<256, 1024, 0, stream>>>(x, fc2_w, fc2_b, ws, out);
}